// Round 1
// baseline (197.612 us; speedup 1.0000x reference)
//
#include <hip/hip_runtime.h>
#include <math.h>

#define NG 16
#define NB 32768
#define ND 512

// Kernel 1: L2-normalize centers (NG x ND) into workspace.
__global__ void normalize_centers_kernel(const float* __restrict__ centers,
                                         float* __restrict__ cnorm) {
    const int g = blockIdx.x;           // 0..15
    const int t = threadIdx.x;          // 0..255, each handles 2 floats
    const float2 v = *reinterpret_cast<const float2*>(centers + g * ND + t * 2);
    float ss = v.x * v.x + v.y * v.y;

    // wave (64-lane) butterfly reduce
    #pragma unroll
    for (int off = 1; off < 64; off <<= 1)
        ss += __shfl_xor(ss, off, 64);

    __shared__ float wsum[4];
    const int lane = t & 63;
    const int wave = t >> 6;
    if (lane == 0) wsum[wave] = ss;
    __syncthreads();
    const float tot = wsum[0] + wsum[1] + wsum[2] + wsum[3];
    const float inv = 1.0f / fmaxf(sqrtf(tot), 1e-12f);

    float2 o;
    o.x = v.x * inv;
    o.y = v.y * inv;
    *reinterpret_cast<float2*>(cnorm + g * ND + t * 2) = o;
}

// Kernel 2: streaming sum of clip(||gf_row - c[g]||^2) over all (g,b) rows.
// One 64-lane wave per row; lane i owns dims [4i..4i+3] and [256+4i..256+4i+3].
__global__ __launch_bounds__(256) void compact_loss_kernel(
        const float* __restrict__ gf,      // (NG, NB, ND)
        const float* __restrict__ cnorm,   // (NG, ND)
        float* __restrict__ out) {
    const int g    = blockIdx.y;
    const int lane = threadIdx.x & 63;
    const int wave = threadIdx.x >> 6;    // 0..3

    // center slice in registers (loaded once; L2/L1 resident)
    const float4 c0 = *reinterpret_cast<const float4*>(cnorm + g * ND + lane * 4);
    const float4 c1 = *reinterpret_cast<const float4*>(cnorm + g * ND + 256 + lane * 4);

    const float* base = gf + (size_t)g * NB * ND;
    const int waves_per_g = gridDim.x * 4;
    const int wid = blockIdx.x * 4 + wave;

    float acc = 0.0f;
    for (int b = wid; b < NB; b += waves_per_g) {
        const float* row = base + (size_t)b * ND;
        const float4 v0 = *reinterpret_cast<const float4*>(row + lane * 4);
        const float4 v1 = *reinterpret_cast<const float4*>(row + 256 + lane * 4);

        float d, s;
        d = v0.x - c0.x; s  = d * d;
        d = v0.y - c0.y; s += d * d;
        d = v0.z - c0.z; s += d * d;
        d = v0.w - c0.w; s += d * d;
        d = v1.x - c1.x; s += d * d;
        d = v1.y - c1.y; s += d * d;
        d = v1.z - c1.z; s += d * d;
        d = v1.w - c1.w; s += d * d;

        // wave butterfly reduce -> every lane holds the row sum
        #pragma unroll
        for (int off = 1; off < 64; off <<= 1)
            s += __shfl_xor(s, off, 64);

        // clip like the reference, then accumulate
        s = fminf(fmaxf(s, 1e-12f), 1e12f);
        acc += s;
    }

    __shared__ float wacc[4];
    if (lane == 0) wacc[wave] = acc;
    __syncthreads();
    if (threadIdx.x == 0) {
        const float tot = (wacc[0] + wacc[1] + wacc[2] + wacc[3])
                          * (1.0f / ((float)NG * (float)NB));
        atomicAdd(out, tot);
    }
}

extern "C" void kernel_launch(void* const* d_in, const int* in_sizes, int n_in,
                              void* d_out, int out_size, void* d_ws, size_t ws_size,
                              hipStream_t stream) {
    const float* gf      = (const float*)d_in[0];   // (16, 32768, 512) f32
    const float* centers = (const float*)d_in[1];   // (16, 512) f32
    float* out           = (float*)d_out;           // scalar f32
    float* cnorm         = (float*)d_ws;            // 16*512 f32 = 32 KB

    // d_out is poisoned by the harness; zero it (async memset is capture-legal)
    hipMemsetAsync(out, 0, sizeof(float) * out_size, stream);

    normalize_centers_kernel<<<dim3(NG), dim3(256), 0, stream>>>(centers, cnorm);

    // 128 blocks per group x 16 groups = 2048 blocks (256 CUs x 8), 4 waves each
    compact_loss_kernel<<<dim3(128, NG), dim3(256), 0, stream>>>(gf, cnorm, out);
}

// Round 2
// 172.656 us; speedup vs baseline: 1.1445x; 1.1445x over previous
//
#include <hip/hip_runtime.h>
#include <math.h>

#define NG 16
#define NB 32768
#define ND 512

typedef float f32x4 __attribute__((ext_vector_type(4)));

// One kernel: fused center-normalize (per-block, L2-hit) + streaming
// sum of clip(||gf_row - c_hat[g]||^2). One 64-lane wave per row pair.
__global__ __launch_bounds__(256) void compact_loss_kernel(
        const float* __restrict__ gf,       // (NG, NB, ND)
        const float* __restrict__ centers,  // (NG, ND)
        float* __restrict__ out) {
    const int g    = blockIdx.y;
    const int t    = threadIdx.x;
    const int lane = t & 63;
    const int wave = t >> 6;                // 0..3

    // --- fused L2-normalization of centers[g] (2 KB, L2-resident) ---
    const float2 cv = *reinterpret_cast<const float2*>(centers + g * ND + t * 2);
    float ss = cv.x * cv.x + cv.y * cv.y;
    #pragma unroll
    for (int off = 1; off < 64; off <<= 1)
        ss += __shfl_xor(ss, off, 64);
    __shared__ float wsum[4];
    if (lane == 0) wsum[wave] = ss;
    __syncthreads();
    const float tot = wsum[0] + wsum[1] + wsum[2] + wsum[3];
    const float inv = 1.0f / fmaxf(sqrtf(tot), 1e-12f);

    // lane's center slice, normalized, in registers
    f32x4 c0 = *reinterpret_cast<const f32x4*>(centers + g * ND + lane * 4);
    f32x4 c1 = *reinterpret_cast<const f32x4*>(centers + g * ND + 256 + lane * 4);
    c0 *= inv;
    c1 *= inv;

    const float* base = gf + (size_t)g * NB * ND;
    const int waves_per_g = gridDim.x * 4;      // 512
    const int wid = blockIdx.x * 4 + wave;

    float acc = 0.0f;
    // 2-row unroll: rows b and b+waves_per_g; 4 independent 16B loads in flight.
    for (int b = wid; b < NB; b += 2 * waves_per_g) {
        const float* rowA = base + (size_t)b * ND;
        const float* rowB = base + (size_t)(b + waves_per_g) * ND;
        const f32x4 a0 = __builtin_nontemporal_load(reinterpret_cast<const f32x4*>(rowA + lane * 4));
        const f32x4 a1 = __builtin_nontemporal_load(reinterpret_cast<const f32x4*>(rowA + 256 + lane * 4));
        const f32x4 b0 = __builtin_nontemporal_load(reinterpret_cast<const f32x4*>(rowB + lane * 4));
        const f32x4 b1 = __builtin_nontemporal_load(reinterpret_cast<const f32x4*>(rowB + 256 + lane * 4));

        float d, sA, sB;
        d = a0.x - c0.x; sA  = d * d;
        d = a0.y - c0.y; sA += d * d;
        d = a0.z - c0.z; sA += d * d;
        d = a0.w - c0.w; sA += d * d;
        d = a1.x - c1.x; sA += d * d;
        d = a1.y - c1.y; sA += d * d;
        d = a1.z - c1.z; sA += d * d;
        d = a1.w - c1.w; sA += d * d;

        d = b0.x - c0.x; sB  = d * d;
        d = b0.y - c0.y; sB += d * d;
        d = b0.z - c0.z; sB += d * d;
        d = b0.w - c0.w; sB += d * d;
        d = b1.x - c1.x; sB += d * d;
        d = b1.y - c1.y; sB += d * d;
        d = b1.z - c1.z; sB += d * d;
        d = b1.w - c1.w; sB += d * d;

        // interleaved wave butterfly reduces (independent chains -> ILP)
        #pragma unroll
        for (int off = 1; off < 64; off <<= 1) {
            sA += __shfl_xor(sA, off, 64);
            sB += __shfl_xor(sB, off, 64);
        }

        sA = fminf(fmaxf(sA, 1e-12f), 1e12f);
        sB = fminf(fmaxf(sB, 1e-12f), 1e12f);
        acc += sA + sB;
    }

    __shared__ float wacc[4];
    if (lane == 0) wacc[wave] = acc;
    __syncthreads();
    if (t == 0) {
        const float totb = (wacc[0] + wacc[1] + wacc[2] + wacc[3])
                           * (1.0f / ((float)NG * (float)NB));
        atomicAdd(out, totb);
    }
}

extern "C" void kernel_launch(void* const* d_in, const int* in_sizes, int n_in,
                              void* d_out, int out_size, void* d_ws, size_t ws_size,
                              hipStream_t stream) {
    const float* gf      = (const float*)d_in[0];   // (16, 32768, 512) f32
    const float* centers = (const float*)d_in[1];   // (16, 512) f32
    float* out           = (float*)d_out;           // scalar f32

    // d_out is poisoned by the harness; zero it (async memset is capture-legal)
    hipMemsetAsync(out, 0, sizeof(float) * out_size, stream);

    // 128 blocks per group x 16 groups = 2048 blocks (256 CUs x 8), 4 waves each
    compact_loss_kernel<<<dim3(128, NG), dim3(256), 0, stream>>>(gf, centers, out);
}